// Round 2
// baseline (1283.504 us; speedup 1.0000x reference)
//
#include <hip/hip_runtime.h>
#include <math.h>
#include <stdint.h>

// Problem constants (from reference): S=4096 tokens, E=64 experts, M=1024,
// num_2nd = E/4 = 16, capacity = 2*ceil(S/num_2nd) = 512.
#define S_TOK 4096
#define N_EXP 64
#define MDIM  1024
#define TB    8                    // tokens per k_gate block
#define CAP   512
#define NBLK_GATE (S_TOK / TB)     // 512

struct TokRec { int idx1; int idx2; float g1; float g2; };

// ---------------- JAX threefry2x32 (key = key(42) = (0,42)) -----------------
__device__ __forceinline__ void tf4(uint32_t& x0, uint32_t& x1,
                                    int r0, int r1, int r2, int r3) {
  x0 += x1; x1 = (x1 << r0) | (x1 >> (32 - r0)); x1 ^= x0;
  x0 += x1; x1 = (x1 << r1) | (x1 >> (32 - r1)); x1 ^= x0;
  x0 += x1; x1 = (x1 << r2) | (x1 >> (32 - r2)); x1 ^= x0;
  x0 += x1; x1 = (x1 << r3) | (x1 >> (32 - r3)); x1 ^= x0;
}

// jax.random.gumbel under jax_threefry_partitionable=True (default since
// JAX 0.4.36): counts = iota(uint64, S*E); per element f:
//   x0 = hi32(f) = 0, x1 = lo32(f) = f;  (y0,y1) = threefry2x32(key, (x0,x1))
//   bits = y0 ^ y1   (32-bit fold)
//   u = bitcast(bits>>9 | 0x3f800000) - 1, clamped to tiny; g = -log(-log u).
__device__ __forceinline__ float jax_gumbel(uint32_t f) {
  const uint32_t k0 = 0u, k1 = 42u;
  const uint32_t k2 = 0x1BD11BDAu ^ 42u;
  uint32_t x0 = 0u + k0;     // counts_hi = 0 (size < 2^32)
  uint32_t x1 = f + k1;      // counts_lo = f
  tf4(x0, x1, 13, 15, 26,  6); x0 += k1; x1 += k2 + 1u;
  tf4(x0, x1, 17, 29, 16, 24); x0 += k2; x1 += k0 + 2u;
  tf4(x0, x1, 13, 15, 26,  6); x0 += k0; x1 += k1 + 3u;
  tf4(x0, x1, 17, 29, 16, 24); x0 += k1; x1 += k2 + 4u;
  tf4(x0, x1, 13, 15, 26,  6); x0 += k2; x1 += k0 + 5u;
  uint32_t bits = x0 ^ x1;
  float u = __uint_as_float((bits >> 9) | 0x3F800000u) - 1.0f;
  u = fmaxf(u, 1.17549435e-38f);   // minval = finfo(float32).tiny
  return -logf(-logf(u));
}

// ---------------- zero-fill of the 1.07 GB output ---------------------------
__global__ __launch_bounds__(256) void k_fill(float* __restrict__ out) {
  float4* p = (float4*)out;
  const size_t n4 = ((size_t)S_TOK * N_EXP * CAP * 2) / 4;  // 67108864
  size_t i = (size_t)blockIdx.x * 256 + threadIdx.x;
  const size_t stride = (size_t)gridDim.x * 256;
  const float4 z = make_float4(0.f, 0.f, 0.f, 0.f);
  for (; i < n4; i += stride) p[i] = z;
  if (blockIdx.x == 0 && threadIdx.x == 0)
    out[(size_t)S_TOK * N_EXP * CAP * 2] = 0.f;  // last scalar (element count is odd)
}

// ---------------- logits + softmax + top1 + gumbel top2 ---------------------
__global__ __launch_bounds__(256) void k_gate(const float* __restrict__ tok,
                                              const float* __restrict__ W,
                                              TokRec* __restrict__ recs,
                                              float* __restrict__ mePart) {
  __shared__ float t_lds[TB * MDIM];          // 32 KB
  __shared__ float logits_l[TB * N_EXP];      // 2 KB
  __shared__ float meAcc[4][N_EXP];           // 1 KB

  const int tid  = threadIdx.x;
  const int wave = tid >> 6;
  const int lane = tid & 63;
  const int tok0 = blockIdx.x * TB;

  // stage 8 token rows (coalesced float4)
  {
    const float4* src = (const float4*)(tok + (size_t)tok0 * MDIM);
    float4* dst = (float4*)t_lds;
    #pragma unroll
    for (int i = 0; i < (TB * MDIM / 4) / 256; ++i)
      dst[tid + i * 256] = src[tid + i * 256];
  }
  __syncthreads();

  // wave w handles expert e = p*4+w each pass; lane strides K
  for (int p = 0; p < N_EXP / 4; ++p) {
    const int e = p * 4 + wave;
    const float* wr = W + (size_t)e * MDIM;
    float acc[TB];
    #pragma unroll
    for (int t = 0; t < TB; ++t) acc[t] = 0.f;
    for (int k = lane; k < MDIM; k += 64) {
      float wv = wr[k];
      #pragma unroll
      for (int t = 0; t < TB; ++t) acc[t] = fmaf(t_lds[t * MDIM + k], wv, acc[t]);
    }
    #pragma unroll
    for (int t = 0; t < TB; ++t) {
      float v = acc[t];
      #pragma unroll
      for (int o = 32; o >= 1; o >>= 1) v += __shfl_xor(v, o, 64);
      if (lane == 0) logits_l[t * N_EXP + e] = v;
    }
  }
  __syncthreads();

  // per-token: softmax over 64 (lane = expert), top1, gumbel top2
  const int e = lane;
  float meLocal = 0.f;
  #pragma unroll
  for (int rep = 0; rep < 2; ++rep) {
    const int t = wave + rep * 4;
    const int s = tok0 + t;
    float x = logits_l[t * N_EXP + e];
    float m = x;
    #pragma unroll
    for (int o = 32; o >= 1; o >>= 1) m = fmaxf(m, __shfl_xor(m, o, 64));
    float ex = expf(x - m);
    float sum = ex;
    #pragma unroll
    for (int o = 32; o >= 1; o >>= 1) sum += __shfl_xor(sum, o, 64);
    float gate = ex / sum;
    meLocal += gate;

    // argmax(gates), ties -> lowest index (jnp.argmax semantics)
    float bv = gate; int bi = e;
    #pragma unroll
    for (int o = 32; o >= 1; o >>= 1) {
      float ov = __shfl_xor(bv, o, 64);
      int   oi = __shfl_xor(bi, o, 64);
      if (ov > bv || (ov == bv && oi < bi)) { bv = ov; bi = oi; }
    }
    const int idx1 = bi;

    float noisy = (e == idx1) ? -INFINITY
                              : (gate + jax_gumbel((uint32_t)(s * N_EXP + e)));
    float bv2 = noisy; int bi2 = e;
    #pragma unroll
    for (int o = 32; o >= 1; o >>= 1) {
      float ov = __shfl_xor(bv2, o, 64);
      int   oi = __shfl_xor(bi2, o, 64);
      if (ov > bv2 || (ov == bv2 && oi < bi2)) { bv2 = ov; bi2 = oi; }
    }
    const int idx2 = bi2;

    float g1 = __shfl(gate, idx1, 64);
    float g2 = __shfl(gate, idx2, 64);
    if (lane == 0) {
      TokRec r; r.idx1 = idx1; r.idx2 = idx2; r.g1 = g1; r.g2 = g2;
      recs[s] = r;
    }
  }
  meAcc[wave][e] = meLocal;
  __syncthreads();
  if (wave == 0)
    mePart[(size_t)blockIdx.x * N_EXP + e] =
        meAcc[0][e] + meAcc[1][e] + meAcc[2][e] + meAcc[3][e];
}

// ---------------- cumsum ranks, capacity, scatter, l_aux --------------------
__global__ __launch_bounds__(1024) void k_finish(const TokRec* __restrict__ recs,
                                                 const float* __restrict__ mePart,
                                                 float* __restrict__ out) {
  __shared__ unsigned short pk_l[S_TOK];      // idx1 | idx2<<8   (8 KB)
  __shared__ unsigned short rank1_l[S_TOK];   // 8 KB
  __shared__ unsigned short rank2_l[S_TOK];   // 8 KB
  __shared__ int   cnt1[16][N_EXP];
  __shared__ int   cnt2[16][N_EXP];
  __shared__ int   off1[16][N_EXP];
  __shared__ int   off2[16][N_EXP];
  __shared__ int   total1_l[N_EXP];
  __shared__ float meAcc[16][N_EXP];
  __shared__ float laux_l[N_EXP];

  const int tid  = threadIdx.x;
  const int wave = tid >> 6;     // 0..15 = chunk
  const int lane = tid & 63;     // = expert in phase A/B

  for (int s = tid; s < S_TOK; s += 1024) {
    TokRec r = recs[s];
    pk_l[s] = (unsigned short)(r.idx1 | (r.idx2 << 8));
  }
  __syncthreads();

  // Phase A: within-chunk sequential ranks (wave = chunk of 256 tokens, lane = expert)
  {
    int c1 = 0, c2 = 0;
    const int s0 = wave * (S_TOK / 16);
    for (int j = 0; j < S_TOK / 16; ++j) {
      const int s = s0 + j;
      const int v  = pk_l[s];
      const int v1 = v & 0xFF;
      const int v2 = v >> 8;
      if (v1 == lane) { rank1_l[s] = (unsigned short)c1; ++c1; }
      if (v2 == lane) { rank2_l[s] = (unsigned short)c2; ++c2; }
    }
    cnt1[wave][lane] = c1;
    cnt2[wave][lane] = c2;
  }
  __syncthreads();

  // Phase B: exclusive scan of chunk counts per expert; locations2 offset by total1
  if (tid < N_EXP) {
    int off = 0;
    #pragma unroll
    for (int w = 0; w < 16; ++w) { off1[w][tid] = off; off += cnt1[w][tid]; }
    total1_l[tid] = off;
    int o2 = off;                       // cumsum(mask2)-1 + sum(mask1)
    #pragma unroll
    for (int w = 0; w < 16; ++w) { off2[w][tid] = o2; o2 += cnt2[w][tid]; }
  }
  __syncthreads();

  // Phase C: capacity drop, renormalize, scatter nonzeros
  float* comb = out + 1;
  float* mask = out + 1 + (size_t)S_TOK * N_EXP * CAP;
  for (int s = tid; s < S_TOK; s += 1024) {
    TokRec r = recs[s];
    const int w  = s / (S_TOK / 16);
    const int l1 = (int)rank1_l[s] + off1[w][r.idx1];
    const int l2 = (int)rank2_l[s] + off2[w][r.idx2];
    const bool k1 = l1 < CAP;
    const bool k2 = l2 < CAP;
    float g1 = k1 ? r.g1 : 0.f;
    float g2 = k2 ? r.g2 : 0.f;
    float denom = fmaxf(g1 + g2, 1.1920929e-07f);   // finfo(float32).eps
    float g1n = g1 / denom;
    float g2n = g2 / denom;
    const size_t base = (size_t)s * N_EXP * CAP;
    if (k1) { size_t o = base + (size_t)r.idx1 * CAP + l1; comb[o] = g1n; mask[o] = 1.0f; }
    if (k2) { size_t o = base + (size_t)r.idx2 * CAP + l2; comb[o] = g2n; mask[o] = 1.0f; }
  }

  // Phase D: l_aux = sum_e (me*ce) / 16 * 64*64  = sum_e Sg[e]*cnt1[e] / 65536
  {
    float a = 0.f;
    for (int b = wave; b < NBLK_GATE; b += 16) a += mePart[(size_t)b * N_EXP + lane];
    meAcc[wave][lane] = a;
  }
  __syncthreads();
  if (tid < N_EXP) {
    float sg = 0.f;
    #pragma unroll
    for (int w = 0; w < 16; ++w) sg += meAcc[w][tid];
    laux_l[tid] = sg * (float)total1_l[tid];
  }
  __syncthreads();
  if (tid == 0) {
    float t = 0.f;
    for (int e2 = 0; e2 < N_EXP; ++e2) t += laux_l[e2];
    out[0] = t * (1.0f / 65536.0f);
  }
}

extern "C" void kernel_launch(void* const* d_in, const int* in_sizes, int n_in,
                              void* d_out, int out_size, void* d_ws, size_t ws_size,
                              hipStream_t stream) {
  const float* tok = (const float*)d_in[0];   // [4096,1024] f32
  const float* W   = (const float*)d_in[1];   // [64,1024]  f32
  float* out = (float*)d_out;                 // [1 + 2*4096*64*512] f32

  TokRec* recs   = (TokRec*)d_ws;                                   // 64 KB
  float*  mePart = (float*)((char*)d_ws + S_TOK * sizeof(TokRec));  // 128 KB

  k_fill  <<<4096, 256, 0, stream>>>(out);
  k_gate  <<<NBLK_GATE, 256, 0, stream>>>(tok, W, recs, mePart);
  k_finish<<<1, 1024, 0, stream>>>(recs, mePart, out);
}

// Round 3
// 1186.282 us; speedup vs baseline: 1.0820x; 1.0820x over previous
//
#include <hip/hip_runtime.h>
#include <math.h>
#include <stdint.h>

// Problem constants (from reference): S=4096 tokens, E=64 experts, M=1024,
// num_2nd = E/4 = 16, capacity = 2*ceil(S/num_2nd) = 512.
#define S_TOK 4096
#define N_EXP 64
#define MDIM  1024
#define TB    8                    // tokens per k_gate block
#define CAP   512
#define NBLK_GATE (S_TOK / TB)     // 512

struct TokRec { int idx1; int idx2; float g1; float g2; };

// ---------------- JAX threefry2x32 (key = key(42) = (0,42)) -----------------
__device__ __forceinline__ void tf4(uint32_t& x0, uint32_t& x1,
                                    int r0, int r1, int r2, int r3) {
  x0 += x1; x1 = (x1 << r0) | (x1 >> (32 - r0)); x1 ^= x0;
  x0 += x1; x1 = (x1 << r1) | (x1 >> (32 - r1)); x1 ^= x0;
  x0 += x1; x1 = (x1 << r2) | (x1 >> (32 - r2)); x1 ^= x0;
  x0 += x1; x1 = (x1 << r3) | (x1 >> (32 - r3)); x1 ^= x0;
}

// jax.random.gumbel under jax_threefry_partitionable=True (default since
// JAX 0.4.36): counts = iota(uint64, S*E); per element f:
//   x0 = hi32(f) = 0, x1 = lo32(f) = f;  (y0,y1) = threefry2x32(key, (x0,x1))
//   bits = y0 ^ y1   (32-bit fold)
//   u = bitcast(bits>>9 | 0x3f800000) - 1, clamped to tiny; g = -log(-log u).
__device__ __forceinline__ float jax_gumbel(uint32_t f) {
  const uint32_t k0 = 0u, k1 = 42u;
  const uint32_t k2 = 0x1BD11BDAu ^ 42u;
  uint32_t x0 = 0u + k0;     // counts_hi = 0 (size < 2^32)
  uint32_t x1 = f + k1;      // counts_lo = f
  tf4(x0, x1, 13, 15, 26,  6); x0 += k1; x1 += k2 + 1u;
  tf4(x0, x1, 17, 29, 16, 24); x0 += k2; x1 += k0 + 2u;
  tf4(x0, x1, 13, 15, 26,  6); x0 += k0; x1 += k1 + 3u;
  tf4(x0, x1, 17, 29, 16, 24); x0 += k1; x1 += k2 + 4u;
  tf4(x0, x1, 13, 15, 26,  6); x0 += k2; x1 += k0 + 5u;
  uint32_t bits = x0 ^ x1;
  float u = __uint_as_float((bits >> 9) | 0x3F800000u) - 1.0f;
  u = fmaxf(u, 1.17549435e-38f);   // minval = finfo(float32).tiny
  return -logf(-logf(u));
}

// ---------------- logits + softmax + top1 + gumbel top2 ---------------------
__global__ __launch_bounds__(256) void k_gate(const float* __restrict__ tok,
                                              const float* __restrict__ W,
                                              TokRec* __restrict__ recs,
                                              float* __restrict__ mePart) {
  __shared__ float t_lds[TB * MDIM];          // 32 KB
  __shared__ float logits_l[TB * N_EXP];      // 2 KB
  __shared__ float meAcc[4][N_EXP];           // 1 KB

  const int tid  = threadIdx.x;
  const int wave = tid >> 6;
  const int lane = tid & 63;
  const int tok0 = blockIdx.x * TB;

  // stage 8 token rows (coalesced float4)
  {
    const float4* src = (const float4*)(tok + (size_t)tok0 * MDIM);
    float4* dst = (float4*)t_lds;
    #pragma unroll
    for (int i = 0; i < (TB * MDIM / 4) / 256; ++i)
      dst[tid + i * 256] = src[tid + i * 256];
  }
  __syncthreads();

  // wave w handles expert e = p*4+w each pass; lane strides K
  for (int p = 0; p < N_EXP / 4; ++p) {
    const int e = p * 4 + wave;
    const float* wr = W + (size_t)e * MDIM;
    float acc[TB];
    #pragma unroll
    for (int t = 0; t < TB; ++t) acc[t] = 0.f;
    for (int k = lane; k < MDIM; k += 64) {
      float wv = wr[k];
      #pragma unroll
      for (int t = 0; t < TB; ++t) acc[t] = fmaf(t_lds[t * MDIM + k], wv, acc[t]);
    }
    #pragma unroll
    for (int t = 0; t < TB; ++t) {
      float v = acc[t];
      #pragma unroll
      for (int o = 32; o >= 1; o >>= 1) v += __shfl_xor(v, o, 64);
      if (lane == 0) logits_l[t * N_EXP + e] = v;
    }
  }
  __syncthreads();

  // per-token: softmax over 64 (lane = expert), top1, gumbel top2
  const int e = lane;
  float meLocal = 0.f;
  #pragma unroll
  for (int rep = 0; rep < 2; ++rep) {
    const int t = wave + rep * 4;
    const int s = tok0 + t;
    float x = logits_l[t * N_EXP + e];
    float m = x;
    #pragma unroll
    for (int o = 32; o >= 1; o >>= 1) m = fmaxf(m, __shfl_xor(m, o, 64));
    float ex = expf(x - m);
    float sum = ex;
    #pragma unroll
    for (int o = 32; o >= 1; o >>= 1) sum += __shfl_xor(sum, o, 64);
    float gate = ex / sum;
    meLocal += gate;

    // argmax(gates), ties -> lowest index (jnp.argmax semantics)
    float bv = gate; int bi = e;
    #pragma unroll
    for (int o = 32; o >= 1; o >>= 1) {
      float ov = __shfl_xor(bv, o, 64);
      int   oi = __shfl_xor(bi, o, 64);
      if (ov > bv || (ov == bv && oi < bi)) { bv = ov; bi = oi; }
    }
    const int idx1 = bi;

    float noisy = (e == idx1) ? -INFINITY
                              : (gate + jax_gumbel((uint32_t)(s * N_EXP + e)));
    float bv2 = noisy; int bi2 = e;
    #pragma unroll
    for (int o = 32; o >= 1; o >>= 1) {
      float ov = __shfl_xor(bv2, o, 64);
      int   oi = __shfl_xor(bi2, o, 64);
      if (ov > bv2 || (ov == bv2 && oi < bi2)) { bv2 = ov; bi2 = oi; }
    }
    const int idx2 = bi2;

    float g1 = __shfl(gate, idx1, 64);
    float g2 = __shfl(gate, idx2, 64);
    if (lane == 0) {
      TokRec r; r.idx1 = idx1; r.idx2 = idx2; r.g1 = g1; r.g2 = g2;
      recs[s] = r;
    }
  }
  meAcc[wave][e] = meLocal;
  __syncthreads();
  if (wave == 0)
    mePart[(size_t)blockIdx.x * N_EXP + e] =
        meAcc[0][e] + meAcc[1][e] + meAcc[2][e] + meAcc[3][e];
}

// ---------------- cumsum ranks, capacity, scatter, l_aux --------------------
__global__ __launch_bounds__(1024) void k_finish(const TokRec* __restrict__ recs,
                                                 const float* __restrict__ mePart,
                                                 float* __restrict__ out) {
  __shared__ unsigned short pk_l[S_TOK];      // idx1 | idx2<<8   (8 KB)
  __shared__ unsigned short rank1_l[S_TOK];   // 8 KB
  __shared__ unsigned short rank2_l[S_TOK];   // 8 KB
  __shared__ int   cnt1[16][N_EXP];
  __shared__ int   cnt2[16][N_EXP];
  __shared__ int   off1[16][N_EXP];
  __shared__ int   off2[16][N_EXP];
  __shared__ int   total1_l[N_EXP];
  __shared__ float meAcc[16][N_EXP];
  __shared__ float laux_l[N_EXP];

  const int tid  = threadIdx.x;
  const int wave = tid >> 6;     // 0..15 = chunk
  const int lane = tid & 63;     // = expert in phase A/B

  for (int s = tid; s < S_TOK; s += 1024) {
    TokRec r = recs[s];
    pk_l[s] = (unsigned short)(r.idx1 | (r.idx2 << 8));
  }
  __syncthreads();

  // Phase A: within-chunk sequential ranks (wave = chunk of 256 tokens, lane = expert)
  {
    int c1 = 0, c2 = 0;
    const int s0 = wave * (S_TOK / 16);
    for (int j = 0; j < S_TOK / 16; ++j) {
      const int s = s0 + j;
      const int v  = pk_l[s];
      const int v1 = v & 0xFF;
      const int v2 = v >> 8;
      if (v1 == lane) { rank1_l[s] = (unsigned short)c1; ++c1; }
      if (v2 == lane) { rank2_l[s] = (unsigned short)c2; ++c2; }
    }
    cnt1[wave][lane] = c1;
    cnt2[wave][lane] = c2;
  }
  __syncthreads();

  // Phase B: exclusive scan of chunk counts per expert; locations2 offset by total1
  if (tid < N_EXP) {
    int off = 0;
    #pragma unroll
    for (int w = 0; w < 16; ++w) { off1[w][tid] = off; off += cnt1[w][tid]; }
    total1_l[tid] = off;
    int o2 = off;                       // cumsum(mask2)-1 + sum(mask1)
    #pragma unroll
    for (int w = 0; w < 16; ++w) { off2[w][tid] = o2; o2 += cnt2[w][tid]; }
  }
  __syncthreads();

  // Phase C: capacity drop, renormalize, scatter nonzeros
  float* comb = out + 1;
  float* mask = out + 1 + (size_t)S_TOK * N_EXP * CAP;
  for (int s = tid; s < S_TOK; s += 1024) {
    TokRec r = recs[s];
    const int w  = s / (S_TOK / 16);
    const int l1 = (int)rank1_l[s] + off1[w][r.idx1];
    const int l2 = (int)rank2_l[s] + off2[w][r.idx2];
    const bool k1 = l1 < CAP;
    const bool k2 = l2 < CAP;
    float g1 = k1 ? r.g1 : 0.f;
    float g2 = k2 ? r.g2 : 0.f;
    float denom = fmaxf(g1 + g2, 1.1920929e-07f);   // finfo(float32).eps
    float g1n = g1 / denom;
    float g2n = g2 / denom;
    const size_t base = (size_t)s * N_EXP * CAP;
    if (k1) { size_t o = base + (size_t)r.idx1 * CAP + l1; comb[o] = g1n; mask[o] = 1.0f; }
    if (k2) { size_t o = base + (size_t)r.idx2 * CAP + l2; comb[o] = g2n; mask[o] = 1.0f; }
  }

  // Phase D: l_aux = sum_e (me*ce) / 16 * 64*64  = sum_e Sg[e]*cnt1[e] / 65536
  {
    float a = 0.f;
    for (int b = wave; b < NBLK_GATE; b += 16) a += mePart[(size_t)b * N_EXP + lane];
    meAcc[wave][lane] = a;
  }
  __syncthreads();
  if (tid < N_EXP) {
    float sg = 0.f;
    #pragma unroll
    for (int w = 0; w < 16; ++w) sg += meAcc[w][tid];
    laux_l[tid] = sg * (float)total1_l[tid];
  }
  __syncthreads();
  if (tid == 0) {
    float t = 0.f;
    for (int e2 = 0; e2 < N_EXP; ++e2) t += laux_l[e2];
    out[0] = t * (1.0f / 65536.0f);
  }
}

extern "C" void kernel_launch(void* const* d_in, const int* in_sizes, int n_in,
                              void* d_out, int out_size, void* d_ws, size_t ws_size,
                              hipStream_t stream) {
  const float* tok = (const float*)d_in[0];   // [4096,1024] f32
  const float* W   = (const float*)d_in[1];   // [64,1024]  f32
  float* out = (float*)d_out;                 // [1 + 2*4096*64*512] f32

  TokRec* recs   = (TokRec*)d_ws;                                   // 64 KB
  float*  mePart = (float*)((char*)d_ws + S_TOK * sizeof(TokRec));  // 128 KB

  // Bulk zero of the 1.07 GB output via the runtime fill path (rocclr
  // fillBufferAligned measured at 6.2 TB/s on this device vs ~2 TB/s for the
  // hand-rolled grid-stride fill). Legal graph-capture node.
  const size_t out_bytes = ((size_t)S_TOK * N_EXP * CAP * 2 + 1) * sizeof(float);
  hipMemsetAsync(out, 0, out_bytes, stream);

  k_gate  <<<NBLK_GATE, 256, 0, stream>>>(tok, W, recs, mePart);
  k_finish<<<1, 1024, 0, stream>>>(recs, mePart, out);
}

// Round 4
// 1181.977 us; speedup vs baseline: 1.0859x; 1.0036x over previous
//
#include <hip/hip_runtime.h>
#include <math.h>
#include <stdint.h>

// Problem constants (from reference): S=4096 tokens, E=64 experts, M=1024,
// num_2nd = E/4 = 16, capacity = 2*ceil(S/num_2nd) = 512.
#define S_TOK 4096
#define N_EXP 64
#define MDIM  1024
#define TB    8                    // tokens per k_gate block
#define CAP   512
#define NBLK_GATE (S_TOK / TB)     // 512

// out layout: [0] = l_aux, [1 .. S*E*C] = combine, [1+S*E*C .. 2*S*E*C] = mask
// total elements = 1 + 2*S*E*C = 268435457 (odd -> 4-byte-aligned total size!)
#define SEC  ((size_t)S_TOK * N_EXP * CAP)       // 134217728
#define OUT_LAST (2 * SEC)                       // index 268435456, the tail elt

struct TokRec { int idx1; int idx2; float g1; float g2; };

// ---------------- JAX threefry2x32 (key = key(42) = (0,42)) -----------------
__device__ __forceinline__ void tf4(uint32_t& x0, uint32_t& x1,
                                    int r0, int r1, int r2, int r3) {
  x0 += x1; x1 = (x1 << r0) | (x1 >> (32 - r0)); x1 ^= x0;
  x0 += x1; x1 = (x1 << r1) | (x1 >> (32 - r1)); x1 ^= x0;
  x0 += x1; x1 = (x1 << r2) | (x1 >> (32 - r2)); x1 ^= x0;
  x0 += x1; x1 = (x1 << r3) | (x1 >> (32 - r3)); x1 ^= x0;
}

// jax.random.gumbel under jax_threefry_partitionable=True (default since
// JAX 0.4.36): counts = iota(uint64, S*E); per element f:
//   x0 = hi32(f) = 0, x1 = lo32(f) = f;  (y0,y1) = threefry2x32(key, (x0,x1))
//   bits = y0 ^ y1; u = bitcast(bits>>9 | 0x3f800000) - 1, clamp tiny;
//   g = -log(-log u).
__device__ __forceinline__ float jax_gumbel(uint32_t f) {
  const uint32_t k0 = 0u, k1 = 42u;
  const uint32_t k2 = 0x1BD11BDAu ^ 42u;
  uint32_t x0 = 0u + k0;     // counts_hi = 0 (size < 2^32)
  uint32_t x1 = f + k1;      // counts_lo = f
  tf4(x0, x1, 13, 15, 26,  6); x0 += k1; x1 += k2 + 1u;
  tf4(x0, x1, 17, 29, 16, 24); x0 += k2; x1 += k0 + 2u;
  tf4(x0, x1, 13, 15, 26,  6); x0 += k0; x1 += k1 + 3u;
  tf4(x0, x1, 17, 29, 16, 24); x0 += k1; x1 += k2 + 4u;
  tf4(x0, x1, 13, 15, 26,  6); x0 += k2; x1 += k0 + 5u;
  uint32_t bits = x0 ^ x1;
  float u = __uint_as_float((bits >> 9) | 0x3F800000u) - 1.0f;
  u = fmaxf(u, 1.17549435e-38f);   // minval = finfo(float32).tiny
  return -logf(-logf(u));
}

// ---------------- logits + softmax + top1 + gumbel top2 ---------------------
__global__ __launch_bounds__(256) void k_gate(const float* __restrict__ tok,
                                              const float* __restrict__ W,
                                              TokRec* __restrict__ recs,
                                              float* __restrict__ mePart) {
  __shared__ float t_lds[TB * MDIM];          // 32 KB
  __shared__ float logits_l[TB * N_EXP];      // 2 KB
  __shared__ float meAcc[4][N_EXP];           // 1 KB

  const int tid  = threadIdx.x;
  const int wave = tid >> 6;
  const int lane = tid & 63;
  const int tok0 = blockIdx.x * TB;

  // stage 8 token rows (coalesced float4)
  {
    const float4* src = (const float4*)(tok + (size_t)tok0 * MDIM);
    float4* dst = (float4*)t_lds;
    #pragma unroll
    for (int i = 0; i < (TB * MDIM / 4) / 256; ++i)
      dst[tid + i * 256] = src[tid + i * 256];
  }
  __syncthreads();

  // wave w handles expert e = p*4+w each pass; lane strides K
  for (int p = 0; p < N_EXP / 4; ++p) {
    const int e = p * 4 + wave;
    const float* wr = W + (size_t)e * MDIM;
    float acc[TB];
    #pragma unroll
    for (int t = 0; t < TB; ++t) acc[t] = 0.f;
    for (int k = lane; k < MDIM; k += 64) {
      float wv = wr[k];
      #pragma unroll
      for (int t = 0; t < TB; ++t) acc[t] = fmaf(t_lds[t * MDIM + k], wv, acc[t]);
    }
    #pragma unroll
    for (int t = 0; t < TB; ++t) {
      float v = acc[t];
      #pragma unroll
      for (int o = 32; o >= 1; o >>= 1) v += __shfl_xor(v, o, 64);
      if (lane == 0) logits_l[t * N_EXP + e] = v;
    }
  }
  __syncthreads();

  // per-token: softmax over 64 (lane = expert), top1, gumbel top2
  const int e = lane;
  float meLocal = 0.f;
  #pragma unroll
  for (int rep = 0; rep < 2; ++rep) {
    const int t = wave + rep * 4;
    const int s = tok0 + t;
    float x = logits_l[t * N_EXP + e];
    float m = x;
    #pragma unroll
    for (int o = 32; o >= 1; o >>= 1) m = fmaxf(m, __shfl_xor(m, o, 64));
    float ex = expf(x - m);
    float sum = ex;
    #pragma unroll
    for (int o = 32; o >= 1; o >>= 1) sum += __shfl_xor(sum, o, 64);
    float gate = ex / sum;
    meLocal += gate;

    // argmax(gates), ties -> lowest index (jnp.argmax semantics)
    float bv = gate; int bi = e;
    #pragma unroll
    for (int o = 32; o >= 1; o >>= 1) {
      float ov = __shfl_xor(bv, o, 64);
      int   oi = __shfl_xor(bi, o, 64);
      if (ov > bv || (ov == bv && oi < bi)) { bv = ov; bi = oi; }
    }
    const int idx1 = bi;

    float noisy = (e == idx1) ? -INFINITY
                              : (gate + jax_gumbel((uint32_t)(s * N_EXP + e)));
    float bv2 = noisy; int bi2 = e;
    #pragma unroll
    for (int o = 32; o >= 1; o >>= 1) {
      float ov = __shfl_xor(bv2, o, 64);
      int   oi = __shfl_xor(bi2, o, 64);
      if (ov > bv2 || (ov == bv2 && oi < bi2)) { bv2 = ov; bi2 = oi; }
    }
    const int idx2 = bi2;

    float g1 = __shfl(gate, idx1, 64);
    float g2 = __shfl(gate, idx2, 64);
    if (lane == 0) {
      TokRec r; r.idx1 = idx1; r.idx2 = idx2; r.g1 = g1; r.g2 = g2;
      recs[s] = r;
    }
  }
  meAcc[wave][e] = meLocal;
  __syncthreads();
  if (wave == 0)
    mePart[(size_t)blockIdx.x * N_EXP + e] =
        meAcc[0][e] + meAcc[1][e] + meAcc[2][e] + meAcc[3][e];
}

// ---------------- cumsum ranks, capacity, scatter, l_aux --------------------
__global__ __launch_bounds__(1024) void k_finish(const TokRec* __restrict__ recs,
                                                 const float* __restrict__ mePart,
                                                 float* __restrict__ out) {
  __shared__ unsigned short pk_l[S_TOK];      // idx1 | idx2<<8   (8 KB)
  __shared__ unsigned short rank1_l[S_TOK];   // 8 KB
  __shared__ unsigned short rank2_l[S_TOK];   // 8 KB
  __shared__ int   cnt1[16][N_EXP];
  __shared__ int   cnt2[16][N_EXP];
  __shared__ int   off1[16][N_EXP];
  __shared__ int   off2[16][N_EXP];
  __shared__ int   total1_l[N_EXP];
  __shared__ float meAcc[16][N_EXP];
  __shared__ float laux_l[N_EXP];

  const int tid  = threadIdx.x;
  const int wave = tid >> 6;     // 0..15 = chunk
  const int lane = tid & 63;     // = expert in phase A/B

  // The bulk memset covers only the first 2^30 bytes (16B-aligned size for the
  // fast rocclr fill path); zero the final odd element here, before the
  // __syncthreads that precedes the Phase-C scatter (which may overwrite it).
  if (tid == 0) out[OUT_LAST] = 0.f;

  for (int s = tid; s < S_TOK; s += 1024) {
    TokRec r = recs[s];
    pk_l[s] = (unsigned short)(r.idx1 | (r.idx2 << 8));
  }
  __syncthreads();

  // Phase A: within-chunk sequential ranks (wave = chunk of 256 tokens, lane = expert)
  {
    int c1 = 0, c2 = 0;
    const int s0 = wave * (S_TOK / 16);
    for (int j = 0; j < S_TOK / 16; ++j) {
      const int s = s0 + j;
      const int v  = pk_l[s];
      const int v1 = v & 0xFF;
      const int v2 = v >> 8;
      if (v1 == lane) { rank1_l[s] = (unsigned short)c1; ++c1; }
      if (v2 == lane) { rank2_l[s] = (unsigned short)c2; ++c2; }
    }
    cnt1[wave][lane] = c1;
    cnt2[wave][lane] = c2;
  }
  __syncthreads();

  // Phase B: exclusive scan of chunk counts per expert; locations2 offset by total1
  if (tid < N_EXP) {
    int off = 0;
    #pragma unroll
    for (int w = 0; w < 16; ++w) { off1[w][tid] = off; off += cnt1[w][tid]; }
    total1_l[tid] = off;
    int o2 = off;                       // cumsum(mask2)-1 + sum(mask1)
    #pragma unroll
    for (int w = 0; w < 16; ++w) { off2[w][tid] = o2; o2 += cnt2[w][tid]; }
  }
  __syncthreads();

  // Phase C: capacity drop, renormalize, scatter nonzeros
  float* comb = out + 1;
  float* mask = out + 1 + SEC;
  for (int s = tid; s < S_TOK; s += 1024) {
    TokRec r = recs[s];
    const int w  = s / (S_TOK / 16);
    const int l1 = (int)rank1_l[s] + off1[w][r.idx1];
    const int l2 = (int)rank2_l[s] + off2[w][r.idx2];
    const bool k1 = l1 < CAP;
    const bool k2 = l2 < CAP;
    float g1 = k1 ? r.g1 : 0.f;
    float g2 = k2 ? r.g2 : 0.f;
    float denom = fmaxf(g1 + g2, 1.1920929e-07f);   // finfo(float32).eps
    float g1n = g1 / denom;
    float g2n = g2 / denom;
    const size_t base = (size_t)s * N_EXP * CAP;
    if (k1) { size_t o = base + (size_t)r.idx1 * CAP + l1; comb[o] = g1n; mask[o] = 1.0f; }
    if (k2) { size_t o = base + (size_t)r.idx2 * CAP + l2; comb[o] = g2n; mask[o] = 1.0f; }
  }

  // Phase D: l_aux = sum_e (me*ce) / 16 * 64*64  = sum_e Sg[e]*cnt1[e] / 65536
  {
    float a = 0.f;
    for (int b = wave; b < NBLK_GATE; b += 16) a += mePart[(size_t)b * N_EXP + lane];
    meAcc[wave][lane] = a;
  }
  __syncthreads();
  if (tid < N_EXP) {
    float sg = 0.f;
    #pragma unroll
    for (int w = 0; w < 16; ++w) sg += meAcc[w][tid];
    laux_l[tid] = sg * (float)total1_l[tid];
  }
  __syncthreads();
  if (tid == 0) {
    float t = 0.f;
    for (int e2 = 0; e2 < N_EXP; ++e2) t += laux_l[e2];
    out[0] = t * (1.0f / 65536.0f);
  }
}

extern "C" void kernel_launch(void* const* d_in, const int* in_sizes, int n_in,
                              void* d_out, int out_size, void* d_ws, size_t ws_size,
                              hipStream_t stream) {
  const float* tok = (const float*)d_in[0];   // [4096,1024] f32
  const float* W   = (const float*)d_in[1];   // [64,1024]  f32
  float* out = (float*)d_out;                 // [1 + 2*4096*64*512] f32

  TokRec* recs   = (TokRec*)d_ws;                                   // 64 KB
  float*  mePart = (float*)((char*)d_ws + S_TOK * sizeof(TokRec));  // 128 KB

  // Bulk zero via the fast rocclr fill path. Total output is 1,073,741,828
  // bytes (odd float count -> only 4B-aligned size, which demotes the fill to
  // a slow dword variant). Instead memset exactly 2^30 bytes (covers elements
  // 0..268435455); k_finish zeroes the final element out[2*S*E*C] itself.
  hipMemsetAsync(out, 0, (size_t)1 << 30, stream);

  k_gate  <<<NBLK_GATE, 256, 0, stream>>>(tok, W, recs, mePart);
  k_finish<<<1, 1024, 0, stream>>>(recs, mePart, out);
}